// Round 22
// baseline (90.057 us; speedup 1.0000x reference)
//
#include <hip/hip_runtime.h>
#include <hip/hip_bf16.h>

#define F 64
#define SLOPE 0.2f
#define NB_SHIFT 8     // 256 nodes per coarse bucket
#define BATCH 4096     // edges per bin block-part
#define SLAB 5120      // slab capacity per bucket (mean 4096, sigma ~64 -> +16σ)

typedef __attribute__((ext_vector_type(8))) short bf16x8;
typedef __attribute__((ext_vector_type(4))) float f32x4;

__device__ inline unsigned short f2bf(float f) {
    unsigned u = __float_as_uint(f);
    unsigned r = (u + 0x7FFFu + ((u >> 16) & 1u)) >> 16;
    return (unsigned short)r;
}

// ---------------- Kernel 0: prep Wp, w1/w2, slab cursors (1 block) ----------
__global__ __launch_bounds__(256) void gat_prep(
    const float* __restrict__ W, const float* __restrict__ a,
    unsigned short* __restrict__ Wp, float* __restrict__ w1,
    float* __restrict__ w2, int* __restrict__ bucketCursor) {
    int tid = threadIdx.x;
    for (int i = tid; i < 512; i += 256) bucketCursor[i] = i * SLAB;

    if (tid < 64) {
#pragma unroll
        for (int f = 0; f < 8; ++f) {
            int cg = f >> 1, kc = f & 1;
            int col = cg * 16 + (tid & 15);
            unsigned short us[8];
#pragma unroll
            for (int j = 0; j < 8; ++j) {
                int k = kc * 32 + (tid >> 4) * 8 + j;
                us[j] = f2bf(W[k * F + col]);
            }
            uint4 pk;
            pk.x = us[0] | ((unsigned)us[1] << 16);
            pk.y = us[2] | ((unsigned)us[3] << 16);
            pk.z = us[4] | ((unsigned)us[5] << 16);
            pk.w = us[6] | ((unsigned)us[7] << 16);
            *(uint4*)&Wp[(f * 64 + tid) * 8] = pk;
        }
    } else if (tid < 128) {
        int k = tid - 64;
        float acc1 = 0.f, acc2 = 0.f;
#pragma unroll
        for (int n = 0; n < F; ++n) {
            float wv = W[k * F + n];
            acc1 = fmaf(wv, a[n], acc1);
            acc2 = fmaf(wv, a[F + n], acc2);
        }
        w1[k] = acc1;
        w2[k] = acc2;
    }
}

// ---------------- Kernel 1: fused [MFMA gemm (512thr)] ∥ [bin partition] ----
__global__ __launch_bounds__(512) void gat_gemm_bin(
    const float* __restrict__ X, const unsigned short* __restrict__ Wp,
    const float* __restrict__ w1, const float* __restrict__ w2,
    unsigned short* __restrict__ hb, float* __restrict__ s1,
    float* __restrict__ s2, int N,
    const int* __restrict__ src, const int* __restrict__ dst,
    int* __restrict__ bucketCursor, unsigned* __restrict__ bucketData, int E,
    int gemmBlocks) {
    __shared__ int hist[512], excl[512], gbase[512], cur[512];
    __shared__ int wsum[8];
    __shared__ int2 staged[BATCH];

    int tid = threadIdx.x;
    int lane = tid & 63, wid = tid >> 6;

    if ((int)blockIdx.x >= gemmBlocks) {
        // ---------------- bin part ----------------
        int base = (blockIdx.x - gemmBlocks) * BATCH;
        int n = E - base;
        if (n > BATCH) n = BATCH;

        hist[tid] = 0;
        __syncthreads();

        int se[8], de[8];
#pragma unroll
        for (int j = 0; j < 8; ++j) {
            int i = base + j * 512 + tid;
            se[j] = -1;
            de[j] = 0;
            if (i < E) {
                se[j] = src[i];
                de[j] = dst[i];
                atomicAdd(&hist[se[j] >> NB_SHIFT], 1);
            }
        }
        __syncthreads();
        int v = hist[tid];
        int x = v;
#pragma unroll
        for (int off = 1; off < 64; off <<= 1) {
            int y = __shfl_up(x, off, 64);
            if (lane >= off) x += y;
        }
        if (lane == 63) wsum[wid] = x;
        __syncthreads();
        int add = 0;
        for (int w = 0; w < 8; ++w)
            if (w < wid) add += wsum[w];
        int ex = add + x - v;
        excl[tid] = ex;
        cur[tid] = ex;
        __syncthreads();
#pragma unroll
        for (int j = 0; j < 8; ++j) {
            if (se[j] >= 0) {
                int b = se[j] >> NB_SHIFT;
                int pos = atomicAdd(&cur[b], 1);
                staged[pos] = make_int2(se[j], de[j]);
            }
        }
        if (v > 0)
            gbase[tid] = atomicAdd(&bucketCursor[tid], v);
        __syncthreads();
        for (int i = tid; i < n; i += 512) {
            int2 p = staged[i];
            int b = p.x >> NB_SHIFT;
            bucketData[gbase[b] + (i - excl[b])] =
                ((unsigned)(p.x & 255) << 24) | (unsigned)p.y;
        }
        return;
    }

    // ---------------- gemm part (one wave per 16-row tile) ----------------
    int rowBase = blockIdx.x * 128 + wid * 16;
    if (rowBase >= N) return;
    int lrow = lane & 15;
    int kg = lane >> 4;
    int row = rowBase + lrow;
    int rclamp = (row < N) ? row : (N - 1);

    const float* xp = &X[(size_t)rclamp * F + kg * 8];
    float4 u0 = *(const float4*)(xp + 0);
    float4 u1 = *(const float4*)(xp + 4);
    float4 u2 = *(const float4*)(xp + 32);
    float4 u3 = *(const float4*)(xp + 36);
    float xr[16] = {u0.x, u0.y, u0.z, u0.w, u1.x, u1.y, u1.z, u1.w,
                    u2.x, u2.y, u2.z, u2.w, u3.x, u3.y, u3.z, u3.w};

    bf16x8 a0, a1;
#pragma unroll
    for (int j = 0; j < 8; ++j) {
        a0[j] = (short)f2bf(xr[j]);
        a1[j] = (short)f2bf(xr[8 + j]);
    }

    bf16x8 bf0 = *(const bf16x8*)&Wp[(0 * 64 + lane) * 8];
    bf16x8 bf1 = *(const bf16x8*)&Wp[(1 * 64 + lane) * 8];
    bf16x8 bf2 = *(const bf16x8*)&Wp[(2 * 64 + lane) * 8];
    bf16x8 bf3 = *(const bf16x8*)&Wp[(3 * 64 + lane) * 8];
    bf16x8 bf4 = *(const bf16x8*)&Wp[(4 * 64 + lane) * 8];
    bf16x8 bf5 = *(const bf16x8*)&Wp[(5 * 64 + lane) * 8];
    bf16x8 bf6 = *(const bf16x8*)&Wp[(6 * 64 + lane) * 8];
    bf16x8 bf7 = *(const bf16x8*)&Wp[(7 * 64 + lane) * 8];

    f32x4 acc0 = {0.f, 0.f, 0.f, 0.f};
    f32x4 acc1v = {0.f, 0.f, 0.f, 0.f};
    f32x4 acc2v = {0.f, 0.f, 0.f, 0.f};
    f32x4 acc3 = {0.f, 0.f, 0.f, 0.f};
    acc0 = __builtin_amdgcn_mfma_f32_16x16x32_bf16(a0, bf0, acc0, 0, 0, 0);
    acc0 = __builtin_amdgcn_mfma_f32_16x16x32_bf16(a1, bf1, acc0, 0, 0, 0);
    acc1v = __builtin_amdgcn_mfma_f32_16x16x32_bf16(a0, bf2, acc1v, 0, 0, 0);
    acc1v = __builtin_amdgcn_mfma_f32_16x16x32_bf16(a1, bf3, acc1v, 0, 0, 0);
    acc2v = __builtin_amdgcn_mfma_f32_16x16x32_bf16(a0, bf4, acc2v, 0, 0, 0);
    acc2v = __builtin_amdgcn_mfma_f32_16x16x32_bf16(a1, bf5, acc2v, 0, 0, 0);
    acc3 = __builtin_amdgcn_mfma_f32_16x16x32_bf16(a0, bf6, acc3, 0, 0, 0);
    acc3 = __builtin_amdgcn_mfma_f32_16x16x32_bf16(a1, bf7, acc3, 0, 0, 0);

#pragma unroll
    for (int r = 0; r < 4; ++r) {
        int ro = rowBase + kg * 4 + r;
        if (ro < N) {
            size_t rb = (size_t)ro * F + lrow;
            hb[rb + 0] = f2bf(acc0[r]);
            hb[rb + 16] = f2bf(acc1v[r]);
            hb[rb + 32] = f2bf(acc2v[r]);
            hb[rb + 48] = f2bf(acc3[r]);
        }
    }

    float4 wa0 = *(const float4*)&w1[kg * 8];
    float4 wa1 = *(const float4*)&w1[kg * 8 + 4];
    float4 wa2 = *(const float4*)&w1[32 + kg * 8];
    float4 wa3 = *(const float4*)&w1[32 + kg * 8 + 4];
    float4 wb0 = *(const float4*)&w2[kg * 8];
    float4 wb1 = *(const float4*)&w2[kg * 8 + 4];
    float4 wb2 = *(const float4*)&w2[32 + kg * 8];
    float4 wb3 = *(const float4*)&w2[32 + kg * 8 + 4];
    float wv1[16] = {wa0.x, wa0.y, wa0.z, wa0.w, wa1.x, wa1.y, wa1.z, wa1.w,
                     wa2.x, wa2.y, wa2.z, wa2.w, wa3.x, wa3.y, wa3.z, wa3.w};
    float wv2[16] = {wb0.x, wb0.y, wb0.z, wb0.w, wb1.x, wb1.y, wb1.z, wb1.w,
                     wb2.x, wb2.y, wb2.z, wb2.w, wb3.x, wb3.y, wb3.z, wb3.w};
    float p = 0.f, q = 0.f;
#pragma unroll
    for (int j = 0; j < 16; ++j) {
        p = fmaf(xr[j], wv1[j], p);
        q = fmaf(xr[j], wv2[j], q);
    }
    p += __shfl_xor(p, 16, 64);
    p += __shfl_xor(p, 32, 64);
    q += __shfl_xor(q, 16, 64);
    q += __shfl_xor(q, 32, 64);
    if (lane < 16 && row < N) {
        s1[row] = p;
        s2[row] = q;
    }
}

// ---------------- Kernel 2: bucket CSR + alpha precompute (LDS-staged) ------
__global__ __launch_bounds__(256) void gat_bucket(
    const int* __restrict__ bucketCursor, const unsigned* __restrict__ bucketData,
    const float* __restrict__ s1, const float* __restrict__ s2,
    int* __restrict__ rowbeg, int* __restrict__ rowend,
    int2* __restrict__ sortedData, int N) {
    __shared__ unsigned edl[SLAB];   // 20 KB: this bucket's packed edges
    __shared__ int cnt[256], cur[256];
    __shared__ float s1l[256];
    __shared__ int wsum[4];
    int b = blockIdx.x;
    int tid = threadIdx.x, lane = tid & 63, wid = tid >> 6;
    int beg = b * SLAB;
    int end = bucketCursor[b];
    int n = end - beg;
    int node0 = b << NB_SHIFT;
    int node = node0 + tid;

    cnt[tid] = 0;
    s1l[tid] = (node < N) ? s1[node] : 0.f;
    __syncthreads();
    for (int i = tid; i < n; i += 256) {
        unsigned w = bucketData[beg + i];
        edl[i] = w;
        atomicAdd(&cnt[w >> 24], 1);
    }
    __syncthreads();
    int v = cnt[tid];
    int x = v;
#pragma unroll
    for (int off = 1; off < 64; off <<= 1) {
        int y = __shfl_up(x, off, 64);
        if (lane >= off) x += y;
    }
    if (lane == 63) wsum[wid] = x;
    __syncthreads();
    int add = 0;
    for (int w = 0; w < 4; ++w)
        if (w < wid) add += wsum[w];
    int excl = add + x - v;
    if (node < N) {
        rowbeg[node] = beg + excl;
        rowend[node] = beg + excl + v;
    }
    cur[tid] = beg + excl;
    __syncthreads();
    for (int i = tid; i < n; i += 256) {
        unsigned w = edl[i];
        int sloc = w >> 24;
        int d = (int)(w & 0xFFFFFFu);
        float t = s1l[sloc] + s2[d];
        t = (t >= 0.f) ? t : SLOPE * t;
        float al = expf(t);
        int pos = atomicAdd(&cur[sloc], 1);
        sortedData[pos] = make_int2(d, __float_as_int(al));
    }
}

#define EDGE_FMA(g, al, A)                                                   \
    A[0] = fmaf(al, __uint_as_float(g.x << 16), A[0]);                       \
    A[1] = fmaf(al, __uint_as_float(g.x & 0xFFFF0000u), A[1]);               \
    A[2] = fmaf(al, __uint_as_float(g.y << 16), A[2]);                       \
    A[3] = fmaf(al, __uint_as_float(g.y & 0xFFFF0000u), A[3]);               \
    A[4] = fmaf(al, __uint_as_float(g.z << 16), A[4]);                       \
    A[5] = fmaf(al, __uint_as_float(g.z & 0xFFFF0000u), A[5]);               \
    A[6] = fmaf(al, __uint_as_float(g.w << 16), A[6]);                       \
    A[7] = fmaf(al, __uint_as_float(g.w & 0xFFFF0000u), A[7]);

// ---------------- Kernel 3: aggregate, 8 nodes/wave, 8-deep gather unroll ---
__global__ __launch_bounds__(256) void gat_aggregate(
    const int* __restrict__ rowbeg, const int* __restrict__ rowend,
    const int2* __restrict__ sortedData,
    const float* __restrict__ s1, const float* __restrict__ s2,
    const unsigned short* __restrict__ hb, float* __restrict__ out, int N) {
    int tid = threadIdx.x;
    int node = blockIdx.x * 32 + (tid >> 3);
    if (node >= N) return;
    const int fo = (tid & 7) * 8;

    int beg = rowbeg[node];
    int end = rowend[node];
    float as = s1[node] + s2[node];
    as = (as >= 0.f) ? as : SLOPE * as;
    as = expf(as);

    float accA[8], accB[8];
    {
        uint4 hv = *(const uint4*)&hb[(size_t)node * F + fo];
        accA[0] = as * __uint_as_float(hv.x << 16);
        accA[1] = as * __uint_as_float(hv.x & 0xFFFF0000u);
        accA[2] = as * __uint_as_float(hv.y << 16);
        accA[3] = as * __uint_as_float(hv.y & 0xFFFF0000u);
        accA[4] = as * __uint_as_float(hv.z << 16);
        accA[5] = as * __uint_as_float(hv.z & 0xFFFF0000u);
        accA[6] = as * __uint_as_float(hv.w << 16);
        accA[7] = as * __uint_as_float(hv.w & 0xFFFF0000u);
    }
#pragma unroll
    for (int i = 0; i < 8; ++i) accB[i] = 0.f;

    float dsum = as;
    int e = beg;
    // peel to even index so int4 (2-pair) loads are 16B-aligned
    if ((e & 1) && e < end) {
        int2 p0 = sortedData[e];
        float a0 = __int_as_float(p0.y);
        dsum += a0;
        uint4 g0 = *(const uint4*)&hb[(size_t)p0.x * F + fo];
        EDGE_FMA(g0, a0, accA);
        ++e;
    }
    // 8-edge unroll: 4 pair-loads + 8 gathers in flight
    for (; e + 8 <= end; e += 8) {
        int4 q0 = *(const int4*)&sortedData[e];
        int4 q1 = *(const int4*)&sortedData[e + 2];
        int4 q2 = *(const int4*)&sortedData[e + 4];
        int4 q3 = *(const int4*)&sortedData[e + 6];
        uint4 g0 = *(const uint4*)&hb[(size_t)q0.x * F + fo];
        uint4 g1 = *(const uint4*)&hb[(size_t)q0.z * F + fo];
        uint4 g2 = *(const uint4*)&hb[(size_t)q1.x * F + fo];
        uint4 g3 = *(const uint4*)&hb[(size_t)q1.z * F + fo];
        uint4 g4 = *(const uint4*)&hb[(size_t)q2.x * F + fo];
        uint4 g5 = *(const uint4*)&hb[(size_t)q2.z * F + fo];
        uint4 g6 = *(const uint4*)&hb[(size_t)q3.x * F + fo];
        uint4 g7 = *(const uint4*)&hb[(size_t)q3.z * F + fo];
        float a0 = __int_as_float(q0.y);
        float a1 = __int_as_float(q0.w);
        float a2 = __int_as_float(q1.y);
        float a3 = __int_as_float(q1.w);
        float a4 = __int_as_float(q2.y);
        float a5 = __int_as_float(q2.w);
        float a6 = __int_as_float(q3.y);
        float a7 = __int_as_float(q3.w);
        dsum += ((a0 + a1) + (a2 + a3)) + ((a4 + a5) + (a6 + a7));
        EDGE_FMA(g0, a0, accA);
        EDGE_FMA(g1, a1, accB);
        EDGE_FMA(g2, a2, accA);
        EDGE_FMA(g3, a3, accB);
        EDGE_FMA(g4, a4, accA);
        EDGE_FMA(g5, a5, accB);
        EDGE_FMA(g6, a6, accA);
        EDGE_FMA(g7, a7, accB);
    }
    for (; e + 4 <= end; e += 4) {
        int4 q0 = *(const int4*)&sortedData[e];
        int4 q1 = *(const int4*)&sortedData[e + 2];
        uint4 g0 = *(const uint4*)&hb[(size_t)q0.x * F + fo];
        uint4 g1 = *(const uint4*)&hb[(size_t)q0.z * F + fo];
        uint4 g2 = *(const uint4*)&hb[(size_t)q1.x * F + fo];
        uint4 g3 = *(const uint4*)&hb[(size_t)q1.z * F + fo];
        float a0 = __int_as_float(q0.y);
        float a1 = __int_as_float(q0.w);
        float a2 = __int_as_float(q1.y);
        float a3 = __int_as_float(q1.w);
        dsum += (a0 + a1) + (a2 + a3);
        EDGE_FMA(g0, a0, accA);
        EDGE_FMA(g1, a1, accB);
        EDGE_FMA(g2, a2, accA);
        EDGE_FMA(g3, a3, accB);
    }
    for (; e < end; ++e) {
        int2 p0 = sortedData[e];
        float a0 = __int_as_float(p0.y);
        dsum += a0;
        uint4 g0 = *(const uint4*)&hb[(size_t)p0.x * F + fo];
        EDGE_FMA(g0, a0, accA);
    }

    float inv = 1.0f / dsum;
    float4 r0, r1;
    r0.x = (accA[0] + accB[0]) * inv;
    r0.y = (accA[1] + accB[1]) * inv;
    r0.z = (accA[2] + accB[2]) * inv;
    r0.w = (accA[3] + accB[3]) * inv;
    r1.x = (accA[4] + accB[4]) * inv;
    r1.y = (accA[5] + accB[5]) * inv;
    r1.z = (accA[6] + accB[6]) * inv;
    r1.w = (accA[7] + accB[7]) * inv;
    *(float4*)&out[(size_t)node * F + fo] = r0;
    *(float4*)&out[(size_t)node * F + fo + 4] = r1;
}

extern "C" void kernel_launch(void* const* d_in, const int* in_sizes, int n_in,
                              void* d_out, int out_size, void* d_ws, size_t ws_size,
                              hipStream_t stream) {
    const float* X = (const float*)d_in[0];
    const int* edge = (const int*)d_in[1];
    const float* W = (const float*)d_in[2];
    const float* a = (const float*)d_in[3];

    int N = in_sizes[0] / F;
    int E = in_sizes[1] / 2;
    int NB = (N + 255) >> NB_SHIFT;   // 256-node buckets (<= 512)

    const int* src = edge;
    const int* dst = edge + E;

    unsigned* bucketData = (unsigned*)d_ws;
    int2* sortedData = (int2*)(bucketData + (size_t)NB * SLAB);
    unsigned short* hb = (unsigned short*)(sortedData + (size_t)NB * SLAB);
    float* s1 = (float*)(hb + (size_t)N * F);
    float* s2 = s1 + N;
    int* rowbeg = (int*)(s2 + N);
    int* rowend = rowbeg + N;
    int* bucketCursor = rowend + N;
    unsigned short* Wp = (unsigned short*)(bucketCursor + 512);
    float* w1 = (float*)(Wp + 4096);
    float* w2 = w1 + 64;

    float* out = (float*)d_out;

    gat_prep<<<1, 256, 0, stream>>>(W, a, Wp, w1, w2, bucketCursor);

    int gemmBlocks = (N + 127) / 128;
    int binBlocks = (E + BATCH - 1) / BATCH;
    gat_gemm_bin<<<gemmBlocks + binBlocks, 512, 0, stream>>>(
        X, Wp, w1, w2, hb, s1, s2, N, src, dst, bucketCursor, bucketData, E,
        gemmBlocks);

    gat_bucket<<<NB, 256, 0, stream>>>(bucketCursor, bucketData, s1, s2,
                                       rowbeg, rowend, sortedData, N);

    int aggBlocks = (N + 31) / 32;
    gat_aggregate<<<aggBlocks, 256, 0, stream>>>(rowbeg, rowend, sortedData,
                                                 s1, s2, hb, out, N);
}

// Round 23
// 86.900 us; speedup vs baseline: 1.0363x; 1.0363x over previous
//
#include <hip/hip_runtime.h>
#include <hip/hip_bf16.h>

#define F 64
#define SLOPE 0.2f
#define NB_SHIFT 8     // 256 nodes per coarse bucket
#define BATCH 4096     // edges per bin block-part
#define SLAB 5120      // slab capacity per bucket (mean 4096, sigma ~64 -> +16σ)

typedef __attribute__((ext_vector_type(8))) short bf16x8;
typedef __attribute__((ext_vector_type(4))) float f32x4;

__device__ inline unsigned short f2bf(float f) {
    unsigned u = __float_as_uint(f);
    unsigned r = (u + 0x7FFFu + ((u >> 16) & 1u)) >> 16;
    return (unsigned short)r;
}

// ---------------- Kernel 0: prep Wp, w1/w2, slab cursors (1 block) ----------
__global__ __launch_bounds__(256) void gat_prep(
    const float* __restrict__ W, const float* __restrict__ a,
    unsigned short* __restrict__ Wp, float* __restrict__ w1,
    float* __restrict__ w2, int* __restrict__ bucketCursor) {
    int tid = threadIdx.x;
    for (int i = tid; i < 512; i += 256) bucketCursor[i] = i * SLAB;

    if (tid < 64) {
#pragma unroll
        for (int f = 0; f < 8; ++f) {
            int cg = f >> 1, kc = f & 1;
            int col = cg * 16 + (tid & 15);
            unsigned short us[8];
#pragma unroll
            for (int j = 0; j < 8; ++j) {
                int k = kc * 32 + (tid >> 4) * 8 + j;
                us[j] = f2bf(W[k * F + col]);
            }
            uint4 pk;
            pk.x = us[0] | ((unsigned)us[1] << 16);
            pk.y = us[2] | ((unsigned)us[3] << 16);
            pk.z = us[4] | ((unsigned)us[5] << 16);
            pk.w = us[6] | ((unsigned)us[7] << 16);
            *(uint4*)&Wp[(f * 64 + tid) * 8] = pk;
        }
    } else if (tid < 128) {
        int k = tid - 64;
        float acc1 = 0.f, acc2 = 0.f;
#pragma unroll
        for (int n = 0; n < F; ++n) {
            float wv = W[k * F + n];
            acc1 = fmaf(wv, a[n], acc1);
            acc2 = fmaf(wv, a[F + n], acc2);
        }
        w1[k] = acc1;
        w2[k] = acc2;
    }
}

// ---------------- Kernel 1: fused [MFMA gemm (512thr)] ∥ [bin partition] ----
__global__ __launch_bounds__(512) void gat_gemm_bin(
    const float* __restrict__ X, const unsigned short* __restrict__ Wp,
    const float* __restrict__ w1, const float* __restrict__ w2,
    unsigned short* __restrict__ hb, float* __restrict__ s1,
    float* __restrict__ s2, int N,
    const int* __restrict__ src, const int* __restrict__ dst,
    int* __restrict__ bucketCursor, unsigned* __restrict__ bucketData, int E,
    int gemmBlocks) {
    __shared__ int hist[512], excl[512], gbase[512], cur[512];
    __shared__ int wsum[8];
    __shared__ int2 staged[BATCH];

    int tid = threadIdx.x;
    int lane = tid & 63, wid = tid >> 6;

    if ((int)blockIdx.x >= gemmBlocks) {
        // ---------------- bin part ----------------
        int base = (blockIdx.x - gemmBlocks) * BATCH;
        int n = E - base;
        if (n > BATCH) n = BATCH;

        hist[tid] = 0;
        __syncthreads();

        int se[8], de[8];
#pragma unroll
        for (int j = 0; j < 8; ++j) {
            int i = base + j * 512 + tid;
            se[j] = -1;
            de[j] = 0;
            if (i < E) {
                se[j] = src[i];
                de[j] = dst[i];
                atomicAdd(&hist[se[j] >> NB_SHIFT], 1);
            }
        }
        __syncthreads();
        int v = hist[tid];
        int x = v;
#pragma unroll
        for (int off = 1; off < 64; off <<= 1) {
            int y = __shfl_up(x, off, 64);
            if (lane >= off) x += y;
        }
        if (lane == 63) wsum[wid] = x;
        __syncthreads();
        int add = 0;
        for (int w = 0; w < 8; ++w)
            if (w < wid) add += wsum[w];
        int ex = add + x - v;
        excl[tid] = ex;
        cur[tid] = ex;
        __syncthreads();
#pragma unroll
        for (int j = 0; j < 8; ++j) {
            if (se[j] >= 0) {
                int b = se[j] >> NB_SHIFT;
                int pos = atomicAdd(&cur[b], 1);
                staged[pos] = make_int2(se[j], de[j]);
            }
        }
        if (v > 0)
            gbase[tid] = atomicAdd(&bucketCursor[tid], v);
        __syncthreads();
        for (int i = tid; i < n; i += 512) {
            int2 p = staged[i];
            int b = p.x >> NB_SHIFT;
            bucketData[gbase[b] + (i - excl[b])] =
                ((unsigned)(p.x & 255) << 24) | (unsigned)p.y;
        }
        return;
    }

    // ---------------- gemm part (one wave per 16-row tile) ----------------
    int rowBase = blockIdx.x * 128 + wid * 16;
    if (rowBase >= N) return;
    int lrow = lane & 15;
    int kg = lane >> 4;
    int row = rowBase + lrow;
    int rclamp = (row < N) ? row : (N - 1);

    const float* xp = &X[(size_t)rclamp * F + kg * 8];
    float4 u0 = *(const float4*)(xp + 0);
    float4 u1 = *(const float4*)(xp + 4);
    float4 u2 = *(const float4*)(xp + 32);
    float4 u3 = *(const float4*)(xp + 36);
    float xr[16] = {u0.x, u0.y, u0.z, u0.w, u1.x, u1.y, u1.z, u1.w,
                    u2.x, u2.y, u2.z, u2.w, u3.x, u3.y, u3.z, u3.w};

    bf16x8 a0, a1;
#pragma unroll
    for (int j = 0; j < 8; ++j) {
        a0[j] = (short)f2bf(xr[j]);
        a1[j] = (short)f2bf(xr[8 + j]);
    }

    bf16x8 bf0 = *(const bf16x8*)&Wp[(0 * 64 + lane) * 8];
    bf16x8 bf1 = *(const bf16x8*)&Wp[(1 * 64 + lane) * 8];
    bf16x8 bf2 = *(const bf16x8*)&Wp[(2 * 64 + lane) * 8];
    bf16x8 bf3 = *(const bf16x8*)&Wp[(3 * 64 + lane) * 8];
    bf16x8 bf4 = *(const bf16x8*)&Wp[(4 * 64 + lane) * 8];
    bf16x8 bf5 = *(const bf16x8*)&Wp[(5 * 64 + lane) * 8];
    bf16x8 bf6 = *(const bf16x8*)&Wp[(6 * 64 + lane) * 8];
    bf16x8 bf7 = *(const bf16x8*)&Wp[(7 * 64 + lane) * 8];

    f32x4 acc0 = {0.f, 0.f, 0.f, 0.f};
    f32x4 acc1v = {0.f, 0.f, 0.f, 0.f};
    f32x4 acc2v = {0.f, 0.f, 0.f, 0.f};
    f32x4 acc3 = {0.f, 0.f, 0.f, 0.f};
    acc0 = __builtin_amdgcn_mfma_f32_16x16x32_bf16(a0, bf0, acc0, 0, 0, 0);
    acc0 = __builtin_amdgcn_mfma_f32_16x16x32_bf16(a1, bf1, acc0, 0, 0, 0);
    acc1v = __builtin_amdgcn_mfma_f32_16x16x32_bf16(a0, bf2, acc1v, 0, 0, 0);
    acc1v = __builtin_amdgcn_mfma_f32_16x16x32_bf16(a1, bf3, acc1v, 0, 0, 0);
    acc2v = __builtin_amdgcn_mfma_f32_16x16x32_bf16(a0, bf4, acc2v, 0, 0, 0);
    acc2v = __builtin_amdgcn_mfma_f32_16x16x32_bf16(a1, bf5, acc2v, 0, 0, 0);
    acc3 = __builtin_amdgcn_mfma_f32_16x16x32_bf16(a0, bf6, acc3, 0, 0, 0);
    acc3 = __builtin_amdgcn_mfma_f32_16x16x32_bf16(a1, bf7, acc3, 0, 0, 0);

#pragma unroll
    for (int r = 0; r < 4; ++r) {
        int ro = rowBase + kg * 4 + r;
        if (ro < N) {
            size_t rb = (size_t)ro * F + lrow;
            hb[rb + 0] = f2bf(acc0[r]);
            hb[rb + 16] = f2bf(acc1v[r]);
            hb[rb + 32] = f2bf(acc2v[r]);
            hb[rb + 48] = f2bf(acc3[r]);
        }
    }

    float4 wa0 = *(const float4*)&w1[kg * 8];
    float4 wa1 = *(const float4*)&w1[kg * 8 + 4];
    float4 wa2 = *(const float4*)&w1[32 + kg * 8];
    float4 wa3 = *(const float4*)&w1[32 + kg * 8 + 4];
    float4 wb0 = *(const float4*)&w2[kg * 8];
    float4 wb1 = *(const float4*)&w2[kg * 8 + 4];
    float4 wb2 = *(const float4*)&w2[32 + kg * 8];
    float4 wb3 = *(const float4*)&w2[32 + kg * 8 + 4];
    float wv1[16] = {wa0.x, wa0.y, wa0.z, wa0.w, wa1.x, wa1.y, wa1.z, wa1.w,
                     wa2.x, wa2.y, wa2.z, wa2.w, wa3.x, wa3.y, wa3.z, wa3.w};
    float wv2[16] = {wb0.x, wb0.y, wb0.z, wb0.w, wb1.x, wb1.y, wb1.z, wb1.w,
                     wb2.x, wb2.y, wb2.z, wb2.w, wb3.x, wb3.y, wb3.z, wb3.w};
    float p = 0.f, q = 0.f;
#pragma unroll
    for (int j = 0; j < 16; ++j) {
        p = fmaf(xr[j], wv1[j], p);
        q = fmaf(xr[j], wv2[j], q);
    }
    p += __shfl_xor(p, 16, 64);
    p += __shfl_xor(p, 32, 64);
    q += __shfl_xor(q, 16, 64);
    q += __shfl_xor(q, 32, 64);
    if (lane < 16 && row < N) {
        s1[row] = p;
        s2[row] = q;
    }
}

// ---------------- Kernel 2: bucket CSR + alpha precompute (LDS-staged) ------
__global__ __launch_bounds__(256) void gat_bucket(
    const int* __restrict__ bucketCursor, const unsigned* __restrict__ bucketData,
    const float* __restrict__ s1, const float* __restrict__ s2,
    int* __restrict__ rowbeg, int* __restrict__ rowend,
    int2* __restrict__ sortedData, int N) {
    __shared__ unsigned edl[SLAB];   // 20 KB: this bucket's packed edges
    __shared__ int cnt[256], cur[256];
    __shared__ float s1l[256];
    __shared__ int wsum[4];
    int b = blockIdx.x;
    int tid = threadIdx.x, lane = tid & 63, wid = tid >> 6;
    int beg = b * SLAB;
    int end = bucketCursor[b];
    int n = end - beg;
    int node0 = b << NB_SHIFT;
    int node = node0 + tid;

    cnt[tid] = 0;
    s1l[tid] = (node < N) ? s1[node] : 0.f;
    __syncthreads();
    for (int i = tid; i < n; i += 256) {
        unsigned w = bucketData[beg + i];
        edl[i] = w;
        atomicAdd(&cnt[w >> 24], 1);
    }
    __syncthreads();
    int v = cnt[tid];
    int x = v;
#pragma unroll
    for (int off = 1; off < 64; off <<= 1) {
        int y = __shfl_up(x, off, 64);
        if (lane >= off) x += y;
    }
    if (lane == 63) wsum[wid] = x;
    __syncthreads();
    int add = 0;
    for (int w = 0; w < 4; ++w)
        if (w < wid) add += wsum[w];
    int excl = add + x - v;
    if (node < N) {
        rowbeg[node] = beg + excl;
        rowend[node] = beg + excl + v;
    }
    cur[tid] = beg + excl;
    __syncthreads();
    for (int i = tid; i < n; i += 256) {
        unsigned w = edl[i];
        int sloc = w >> 24;
        int d = (int)(w & 0xFFFFFFu);
        float t = s1l[sloc] + s2[d];
        t = (t >= 0.f) ? t : SLOPE * t;
        float al = expf(t);
        int pos = atomicAdd(&cur[sloc], 1);
        sortedData[pos] = make_int2(d, __float_as_int(al));
    }
}

#define EDGE_FMA(g, al, A)                                                   \
    A[0] = fmaf(al, __uint_as_float(g.x << 16), A[0]);                       \
    A[1] = fmaf(al, __uint_as_float(g.x & 0xFFFF0000u), A[1]);               \
    A[2] = fmaf(al, __uint_as_float(g.y << 16), A[2]);                       \
    A[3] = fmaf(al, __uint_as_float(g.y & 0xFFFF0000u), A[3]);               \
    A[4] = fmaf(al, __uint_as_float(g.z << 16), A[4]);                       \
    A[5] = fmaf(al, __uint_as_float(g.z & 0xFFFF0000u), A[5]);               \
    A[6] = fmaf(al, __uint_as_float(g.w << 16), A[6]);                       \
    A[7] = fmaf(al, __uint_as_float(g.w & 0xFFFF0000u), A[7]);

// ---------------- Kernel 3: aggregate, 8 nodes/wave, int4 pair loads --------
__global__ __launch_bounds__(256) void gat_aggregate(
    const int* __restrict__ rowbeg, const int* __restrict__ rowend,
    const int2* __restrict__ sortedData,
    const float* __restrict__ s1, const float* __restrict__ s2,
    const unsigned short* __restrict__ hb, float* __restrict__ out, int N) {
    int tid = threadIdx.x;
    int node = blockIdx.x * 32 + (tid >> 3);
    if (node >= N) return;
    const int fo = (tid & 7) * 8;

    int beg = rowbeg[node];
    int end = rowend[node];
    float as = s1[node] + s2[node];
    as = (as >= 0.f) ? as : SLOPE * as;
    as = expf(as);

    float accA[8], accB[8];
    {
        uint4 hv = *(const uint4*)&hb[(size_t)node * F + fo];
        accA[0] = as * __uint_as_float(hv.x << 16);
        accA[1] = as * __uint_as_float(hv.x & 0xFFFF0000u);
        accA[2] = as * __uint_as_float(hv.y << 16);
        accA[3] = as * __uint_as_float(hv.y & 0xFFFF0000u);
        accA[4] = as * __uint_as_float(hv.z << 16);
        accA[5] = as * __uint_as_float(hv.z & 0xFFFF0000u);
        accA[6] = as * __uint_as_float(hv.w << 16);
        accA[7] = as * __uint_as_float(hv.w & 0xFFFF0000u);
    }
#pragma unroll
    for (int i = 0; i < 8; ++i) accB[i] = 0.f;

    float dsum = as;
    int e = beg;
    // peel to even index so int4 (2-pair) loads are 16B-aligned
    if ((e & 1) && e < end) {
        int2 p0 = sortedData[e];
        float a0 = __int_as_float(p0.y);
        dsum += a0;
        uint4 g0 = *(const uint4*)&hb[(size_t)p0.x * F + fo];
        EDGE_FMA(g0, a0, accA);
        ++e;
    }
    for (; e + 4 <= end; e += 4) {
        int4 q0 = *(const int4*)&sortedData[e];      // d0,a0,d1,a1
        int4 q1 = *(const int4*)&sortedData[e + 2];  // d2,a2,d3,a3
        uint4 g0 = *(const uint4*)&hb[(size_t)q0.x * F + fo];
        uint4 g1 = *(const uint4*)&hb[(size_t)q0.z * F + fo];
        uint4 g2 = *(const uint4*)&hb[(size_t)q1.x * F + fo];
        uint4 g3 = *(const uint4*)&hb[(size_t)q1.z * F + fo];
        float a0 = __int_as_float(q0.y);
        float a1 = __int_as_float(q0.w);
        float a2 = __int_as_float(q1.y);
        float a3 = __int_as_float(q1.w);
        dsum += (a0 + a1) + (a2 + a3);
        EDGE_FMA(g0, a0, accA);
        EDGE_FMA(g1, a1, accB);
        EDGE_FMA(g2, a2, accA);
        EDGE_FMA(g3, a3, accB);
    }
    for (; e < end; ++e) {
        int2 p0 = sortedData[e];
        float a0 = __int_as_float(p0.y);
        dsum += a0;
        uint4 g0 = *(const uint4*)&hb[(size_t)p0.x * F + fo];
        EDGE_FMA(g0, a0, accA);
    }

    float inv = 1.0f / dsum;
    float4 r0, r1;
    r0.x = (accA[0] + accB[0]) * inv;
    r0.y = (accA[1] + accB[1]) * inv;
    r0.z = (accA[2] + accB[2]) * inv;
    r0.w = (accA[3] + accB[3]) * inv;
    r1.x = (accA[4] + accB[4]) * inv;
    r1.y = (accA[5] + accB[5]) * inv;
    r1.z = (accA[6] + accB[6]) * inv;
    r1.w = (accA[7] + accB[7]) * inv;
    *(float4*)&out[(size_t)node * F + fo] = r0;
    *(float4*)&out[(size_t)node * F + fo + 4] = r1;
}

extern "C" void kernel_launch(void* const* d_in, const int* in_sizes, int n_in,
                              void* d_out, int out_size, void* d_ws, size_t ws_size,
                              hipStream_t stream) {
    const float* X = (const float*)d_in[0];
    const int* edge = (const int*)d_in[1];
    const float* W = (const float*)d_in[2];
    const float* a = (const float*)d_in[3];

    int N = in_sizes[0] / F;
    int E = in_sizes[1] / 2;
    int NB = (N + 255) >> NB_SHIFT;   // 256-node buckets (<= 512)

    const int* src = edge;
    const int* dst = edge + E;

    unsigned* bucketData = (unsigned*)d_ws;
    int2* sortedData = (int2*)(bucketData + (size_t)NB * SLAB);
    unsigned short* hb = (unsigned short*)(sortedData + (size_t)NB * SLAB);
    float* s1 = (float*)(hb + (size_t)N * F);
    float* s2 = s1 + N;
    int* rowbeg = (int*)(s2 + N);
    int* rowend = rowbeg + N;
    int* bucketCursor = rowend + N;
    unsigned short* Wp = (unsigned short*)(bucketCursor + 512);
    float* w1 = (float*)(Wp + 4096);
    float* w2 = w1 + 64;

    float* out = (float*)d_out;

    gat_prep<<<1, 256, 0, stream>>>(W, a, Wp, w1, w2, bucketCursor);

    int gemmBlocks = (N + 127) / 128;
    int binBlocks = (E + BATCH - 1) / BATCH;
    gat_gemm_bin<<<gemmBlocks + binBlocks, 512, 0, stream>>>(
        X, Wp, w1, w2, hb, s1, s2, N, src, dst, bucketCursor, bucketData, E,
        gemmBlocks);

    gat_bucket<<<NB, 256, 0, stream>>>(bucketCursor, bucketData, s1, s2,
                                       rowbeg, rowend, sortedData, N);

    int aggBlocks = (N + 31) / 32;
    gat_aggregate<<<aggBlocks, 256, 0, stream>>>(rowbeg, rowend, sortedData,
                                                 s1, s2, hb, out, N);
}